// Round 10
// baseline (722.983 us; speedup 1.0000x reference)
//
#include <hip/hip_runtime.h>
#include <hip/hip_bf16.h>

// SectorGCN R17: layer-2 via fire-and-forget global atomics.
// Evidence model (R7-R16): (1) scattered LOADS serialize at ~53cy/line/CU
//   (gather1's 276us wall, invariant over 6 structures); (2) coalesced-RUN
//   scatter writes (Ascatter-style write-out) produce fully-written lines that
//   read back at >1 TB/s (R11 skeleton arm); (3) fine-grained partial-line
//   scatter writes (R13 he 2/line, R16 qe 32/line) read back at ~250 GB/s --
//   R16's qe machinery regressed the total to 635us.
// Fix: out[c] = b2 + dinv[c]*(qq[c] + sum_e ew*qq[r]).  Rscatter2 builds
//   row-sorted rdata=(col|rrem<<20, ew) with Ascatter-style run writes;
//   gather2s stages qq[64] + rdata chunks dense in LDS and does
//   atomicAdd(&o2[col], ew*qq[r]) -- no-return atomics on the fast store path;
//   fin2 finishes densely. pos/qe deleted. Layer-1 unchanged (276us wall).
// Workspace ~82 MB (< 115 MB HW-proven). N=100000, E=3200000.

#define DH 16
#define BSH 6
#define BNODES 64
#define NB_MAX 1568
#define CHUNK 4096        // scatter chunk
#define HCHUNK 8192       // hist chunk
#define NSLICE 4          // gather1 slices
#define SE_CAP 768        // gather1 staged edges per chunk
#define CH2 1024          // gather2s staged edges per chunk

#define BFL(u) __uint_as_float((u) << 16)
#define BFH(u) __uint_as_float((u) & 0xFFFF0000u)

typedef unsigned int u32x2 __attribute__((ext_vector_type(2)));

static __device__ __forceinline__ uint2 ntload_u2(const uint2* p) {
    u32x2 v = __builtin_nontemporal_load((const u32x2*)p);
    return make_uint2(v.x, v.y);
}

// histogram of BOTH col-buckets and row-buckets in one pass
__global__ __launch_bounds__(256) void k_hist2(const int* __restrict__ row,
                                               const int* __restrict__ col,
                                               int* __restrict__ gCnt,
                                               int* __restrict__ rCnt, int E, int NB) {
    __shared__ int lc[NB_MAX];
    __shared__ int lr[NB_MAX];
    const int tid = threadIdx.x;
    for (int i = tid; i < NB; i += 256) { lc[i] = 0; lr[i] = 0; }
    __syncthreads();
    const int base = blockIdx.x * HCHUNK;
    #pragma unroll
    for (int k = 0; k < 32; ++k) {
        int e = base + tid + 256 * k;
        if (e < E) {
            atomicAdd(&lc[col[e] >> BSH], 1);
            atomicAdd(&lr[row[e] >> BSH], 1);
        }
    }
    __syncthreads();
    for (int i = tid; i < NB; i += 256) {
        if (lc[i]) atomicAdd(&gCnt[i], lc[i]);
        if (lr[i]) atomicAdd(&rCnt[i], lr[i]);
    }
}

// exclusive scan of cnt[NB], NB <= 2048 (2 elems/thread)
__global__ __launch_bounds__(1024) void k_Ascan(const int* __restrict__ cnt,
                                                int* __restrict__ basep,
                                                int* __restrict__ cursor,
                                                int NB, int E) {
    __shared__ int s[1024];
    const int t = threadIdx.x;
    const int i0 = 2 * t, i1 = 2 * t + 1;
    int a = (i0 < NB) ? cnt[i0] : 0;
    int b = (i1 < NB) ? cnt[i1] : 0;
    int v = a + b;
    s[t] = v;
    __syncthreads();
    for (int off = 1; off < 1024; off <<= 1) {
        int u = (t >= off) ? s[t - off] : 0;
        __syncthreads();
        s[t] += u;
        __syncthreads();
    }
    int ex = s[t] - v;
    if (i0 < NB) { basep[i0] = ex;     cursor[i0] = ex; }
    if (i1 < NB) { basep[i1] = ex + a; cursor[i1] = ex + a; }
    if (t == 0) basep[NB] = E;
}

// col-sort scatter (R7/R12 body): count -> local scan -> run reservation ->
// sort in LDS -> coalesced-run write-out (full lines; fast read-back).
__global__ __launch_bounds__(256) void k_Ascatter(const int* __restrict__ row,
                                                  const int* __restrict__ col,
                                                  const float* __restrict__ ew,
                                                  int* __restrict__ gCursor,
                                                  uint2* __restrict__ edata,
                                                  int E, int NB) {
    __shared__ int lh[NB_MAX];      // counts, then (globalRun - localBase)
    __shared__ int lbase[NB_MAX];
    __shared__ int lcur[NB_MAX];
    __shared__ int tsum[256];
    __shared__ unsigned short sbuck[CHUNK];
    __shared__ uint2 stage[CHUNK];  // 32 KB
    const int tid = threadIdx.x;
    for (int i = tid; i < NB; i += 256) lh[i] = 0;
    __syncthreads();
    const int base = blockIdx.x * CHUNK;
    int r_[16], c_[16];
    float w_[16];
    #pragma unroll
    for (int k = 0; k < 16; ++k) {
        int e = base + tid + 256 * k;
        bool ok = e < E;
        c_[k] = ok ? col[e] : -1;
        r_[k] = ok ? row[e] : 0;
        w_[k] = ok ? ew[e] : 0.f;
        if (ok) atomicAdd(&lh[c_[k] >> BSH], 1);
    }
    __syncthreads();
    const int t0 = tid * 8;
    int c8[8];
    int mysum = 0;
    #pragma unroll
    for (int k = 0; k < 8; ++k) {
        c8[k] = (t0 + k < NB) ? lh[t0 + k] : 0;
        mysum += c8[k];
    }
    tsum[tid] = mysum;
    __syncthreads();
    for (int off = 1; off < 256; off <<= 1) {
        int u = (tid >= off) ? tsum[tid - off] : 0;
        __syncthreads();
        tsum[tid] += u;
        __syncthreads();
    }
    int p = tsum[tid] - mysum;
    #pragma unroll
    for (int k = 0; k < 8; ++k) {
        if (t0 + k < NB) { lbase[t0 + k] = p; lcur[t0 + k] = p; }
        p += c8[k];
    }
    __syncthreads();
    for (int b = tid; b < NB; b += 256) {
        int cnt = lh[b];
        if (cnt) {
            int g = atomicAdd(&gCursor[b], cnt);
            lh[b] = g - lbase[b];
        }
    }
    __syncthreads();
    #pragma unroll
    for (int k = 0; k < 16; ++k) {
        if (c_[k] >= 0) {
            int b = c_[k] >> BSH;
            unsigned rem = (unsigned)(c_[k] & (BNODES - 1));
            int sp = atomicAdd(&lcur[b], 1);
            stage[sp] = make_uint2((unsigned)r_[k] | (rem << 20), __float_as_uint(w_[k]));
            sbuck[sp] = (unsigned short)b;
        }
    }
    __syncthreads();
    int nE = E - base;
    if (nE > CHUNK) nE = CHUNK;
    for (int j = tid; j < nE; j += 256)
        edata[lh[sbuck[j]] + j] = stage[j];
}

// row-sort scatter: key = row bucket; payload = (col | row_rem<<20, ew).
// Same coalesced-run write-out as Ascatter (full lines; fast read-back).
__global__ __launch_bounds__(256) void k_Rscatter2(const int* __restrict__ row,
                                                   const int* __restrict__ col,
                                                   const float* __restrict__ ew,
                                                   int* __restrict__ rCursor,
                                                   uint2* __restrict__ rdata,
                                                   int E, int NB) {
    __shared__ int lh[NB_MAX];
    __shared__ int lbase[NB_MAX];
    __shared__ int lcur[NB_MAX];
    __shared__ int tsum[256];
    __shared__ unsigned short sbuck[CHUNK];
    __shared__ uint2 stage[CHUNK];  // 32 KB
    const int tid = threadIdx.x;
    for (int i = tid; i < NB; i += 256) lh[i] = 0;
    __syncthreads();
    const int base = blockIdx.x * CHUNK;
    int r_[16], c_[16];
    float w_[16];
    #pragma unroll
    for (int k = 0; k < 16; ++k) {
        int e = base + tid + 256 * k;
        bool ok = e < E;
        r_[k] = ok ? row[e] : -1;
        c_[k] = ok ? col[e] : 0;
        w_[k] = ok ? ew[e] : 0.f;
        if (ok) atomicAdd(&lh[r_[k] >> BSH], 1);
    }
    __syncthreads();
    const int t0 = tid * 8;
    int c8[8];
    int mysum = 0;
    #pragma unroll
    for (int k = 0; k < 8; ++k) {
        c8[k] = (t0 + k < NB) ? lh[t0 + k] : 0;
        mysum += c8[k];
    }
    tsum[tid] = mysum;
    __syncthreads();
    for (int off = 1; off < 256; off <<= 1) {
        int u = (tid >= off) ? tsum[tid - off] : 0;
        __syncthreads();
        tsum[tid] += u;
        __syncthreads();
    }
    int p = tsum[tid] - mysum;
    #pragma unroll
    for (int k = 0; k < 8; ++k) {
        if (t0 + k < NB) { lbase[t0 + k] = p; lcur[t0 + k] = p; }
        p += c8[k];
    }
    __syncthreads();
    for (int bb = tid; bb < NB; bb += 256) {
        int cnt = lh[bb];
        if (cnt) {
            int g = atomicAdd(&rCursor[bb], cnt);
            lh[bb] = g - lbase[bb];
        }
    }
    __syncthreads();
    #pragma unroll
    for (int k = 0; k < 16; ++k) {
        if (r_[k] >= 0) {
            int bb = r_[k] >> BSH;
            uint rrem = (uint)(r_[k] & (BNODES - 1));
            int sp = atomicAdd(&lcur[bb], 1);
            stage[sp] = make_uint2((uint)c_[k] | (rrem << 20), __float_as_uint(w_[k]));
            sbuck[sp] = (unsigned short)bb;
        }
    }
    __syncthreads();
    int nE = E - base;
    if (nE > CHUNK) nE = CHUNK;
    for (int j = tid; j < nE; j += 256)
        rdata[lh[sbuck[j]] + j] = stage[j];
}

// sliced degree: dg[rem] partial in LDS, one global atomic per node per slice
__global__ __launch_bounds__(256) void k_deg(const int* __restrict__ gBase,
                                             const uint2* __restrict__ edata,
                                             float* __restrict__ deg, int N) {
    __shared__ float dg[BNODES];
    const int tid = threadIdx.x;
    if (tid < BNODES) dg[tid] = 0.f;
    __syncthreads();
    const int b = blockIdx.x;
    const int s = gBase[b], e = gBase[b + 1];
    for (int i = s + blockIdx.y * 256 + tid; i < e; i += 512) {
        uint2 ed = ntload_u2(&edata[i]);
        atomicAdd(&dg[ed.x >> 20], __uint_as_float(ed.y));
    }
    __syncthreads();
    int node = (b << BSH) + tid;
    if (tid < BNODES && node < N && dg[tid] != 0.f)
        atomicAdd(&deg[node], dg[tid]);
}

// h~ = rsqrt(deg+1) * (x @ W1) stored as bf16; also stores dinv (fp32).
__global__ __launch_bounds__(256) void k_h1(const float* __restrict__ x,
                                            const float* __restrict__ W1,
                                            const float* __restrict__ deg,
                                            float* __restrict__ dinv,
                                            __hip_bfloat16* __restrict__ hdb) {
    __shared__ float Ws[128 * DH];
    __shared__ float xs[16 * 132];
    const int t = threadIdx.x;
    const int node0 = blockIdx.x * 16;
    #pragma unroll
    for (int i = 0; i < 8; ++i) Ws[t + 256 * i] = W1[t + 256 * i];
    const float4* xg = (const float4*)(x + (size_t)node0 * 128);
    #pragma unroll
    for (int it = 0; it < 2; ++it) {
        int idx = t + 256 * it;
        int n = idx >> 5, k4 = idx & 31;
        float4 v = xg[n * 32 + k4];
        *(float4*)(&xs[n * 132 + k4 * 4]) = v;
    }
    __syncthreads();
    const int node = t >> 4, feat = t & 15;
    const float* xr = &xs[node * 132];
    float acc = 0.f;
    #pragma unroll 8
    for (int k = 0; k < 128; ++k) acc += xr[k] * Ws[k * DH + feat];
    const int v = node0 + node;
    const float di = rsqrtf(deg[v] + 1.0f);
    if (feat == 0) dinv[v] = di;
    hdb[(size_t)v * DH + feat] = __float2bfloat16(di * acc);
}

// layer-1 gather (the 276us wall, proven body): LDS-staged edata + unroll-8
// tiles; 32 groups x 8 lanes, each lane a bf16x2 feature pair (4B gather).
__global__ __launch_bounds__(256) void k_gather1(
    const int* __restrict__ gBase, const uint2* __restrict__ edata,
    const __hip_bfloat16* __restrict__ hdb, float* __restrict__ partial) {
    __shared__ float acc[BNODES][DH + 1];
    __shared__ uint2 se[SE_CAP];
    const int tid = threadIdx.x;
    for (int i = tid; i < BNODES * (DH + 1); i += 256) ((float*)acc)[i] = 0.f;
    const int b = blockIdx.x, sl = blockIdx.y;
    const int s = gBase[b], e = gBase[b + 1];
    const int L = e - s;
    const int per = (L + NSLICE - 1) / NSLICE;
    const int s0 = s + sl * per;
    const int e0 = (s0 + per < e) ? (s0 + per) : e;
    const int g = tid >> 3;        // 0..31: edge slot within tile
    const int f2 = tid & 7;        // feature pair: feats {2*f2, 2*f2+1}
    const uint* __restrict__ hp = (const uint*)hdb;   // node r: hp[r*8 + f2]

    for (int c0 = s0; c0 < e0; c0 += SE_CAP) {
        const int len = ((e0 - c0) < SE_CAP) ? (e0 - c0) : SE_CAP;
        __syncthreads();           // acc-init done / previous se reads done
        for (int j = tid; j < len; j += 256) se[j] = ntload_u2(&edata[c0 + j]);
        __syncthreads();
        const int nfull = len & ~255;
        for (int j0 = 0; j0 < nfull; j0 += 256) {
            uint2 ed[8];
            uint hv[8];
            #pragma unroll
            for (int k = 0; k < 8; ++k) ed[k] = se[j0 + g + k * 32];
            #pragma unroll
            for (int k = 0; k < 8; ++k)
                hv[k] = hp[(size_t)(ed[k].x & 0xFFFFFu) * 8 + f2];
            #pragma unroll
            for (int k = 0; k < 8; ++k) {
                const float w = __uint_as_float(ed[k].y);
                const int rem = ed[k].x >> 20;
                atomicAdd(&acc[rem][2 * f2],     w * BFL(hv[k]));
                atomicAdd(&acc[rem][2 * f2 + 1], w * BFH(hv[k]));
            }
        }
        for (int j = nfull + g; j < len; j += 32) {
            const uint2 ed = se[j];
            const uint hv = hp[(size_t)(ed.x & 0xFFFFFu) * 8 + f2];
            const float w = __uint_as_float(ed.y);
            const int rem = ed.x >> 20;
            atomicAdd(&acc[rem][2 * f2],     w * BFL(hv));
            atomicAdd(&acc[rem][2 * f2 + 1], w * BFH(hv));
        }
    }
    __syncthreads();
    float* ps = partial + ((size_t)b * NSLICE + sl) * (DH * BNODES);
    for (int i = tid; i < DH * BNODES; i += 256)
        ps[i] = acc[i >> 4][i & 15];
}

// reduce slices + self-loop + bias + relu + dot(W2) -> qq[node] (fp32, dense)
__global__ __launch_bounds__(256) void k_fin1b(
    const float* __restrict__ partial, const float* __restrict__ dinv,
    const __hip_bfloat16* __restrict__ hdb, const float* __restrict__ b1,
    const float* __restrict__ W2,
    float* __restrict__ qb, int N) {
    __shared__ float acc[BNODES][DH + 1];
    __shared__ float b1s[DH], W2s[DH];
    const int tid = threadIdx.x;
    if (tid < DH) { b1s[tid] = b1[tid]; W2s[tid] = W2[tid]; }
    const int b = blockIdx.x;
    const float* ps = partial + (size_t)b * NSLICE * (DH * BNODES);
    for (int i = tid; i < DH * BNODES; i += 256) {
        float s = 0.f;
        #pragma unroll
        for (int sl = 0; sl < NSLICE; ++sl) s += ps[sl * (DH * BNODES) + i];
        acc[i >> 4][i & 15] = s;
    }
    __syncthreads();
    int node = (b << BSH) + tid;
    if (tid < BNODES && node < N) {
        float dc = dinv[node];
        const __hip_bfloat16* hs = hdb + (size_t)node * DH;
        float t = 0.f;
        #pragma unroll
        for (int f = 0; f < DH; ++f) {
            float hv = __bfloat162float(hs[f]);
            t += fmaxf(dc * (acc[tid][f] + hv) + b1s[f], 0.f) * W2s[f];
        }
        qb[node] = dc * t;     // qq = dinv[node] * (relu(...) @ W2)
    }
}

// layer-2 scatter: per row-bucket, stage qq[64] (dense 256B) + rdata chunks
// (dense LDS-staged); per edge: atomicAdd(&o2[col], ew*qq[rrem]) --
// fire-and-forget global atomics on the fast store path.
__global__ __launch_bounds__(256) void k_gather2s(
    const int* __restrict__ rBase, const uint2* __restrict__ rdata,
    const float* __restrict__ qb, float* __restrict__ o2, int N) {
    __shared__ float qls[BNODES];
    __shared__ uint2 se[CH2];      // 8 KB
    const int tid = threadIdx.x;
    if (tid < BNODES) {
        int node = (blockIdx.x << BSH) + tid;
        qls[tid] = (node < N) ? qb[node] : 0.f;
    }
    const int b = blockIdx.x;
    const int s = rBase[b], e = rBase[b + 1];
    const int L = e - s;
    const int per = (L + 1) >> 1;
    const int s0 = s + blockIdx.y * per;
    const int e0 = (s0 + per < e) ? (s0 + per) : e;

    for (int c0 = s0; c0 < e0; c0 += CH2) {
        const int len = ((e0 - c0) < CH2) ? (e0 - c0) : CH2;
        __syncthreads();
        for (int i = tid; i < len; i += 256) se[i] = ntload_u2(&rdata[c0 + i]);
        __syncthreads();
        #pragma unroll
        for (int k = 0; k < CH2 / 256; ++k) {
            const int idx = tid + k * 256;
            if (idx < len) {
                const uint2 ed = se[idx];
                const float v = __uint_as_float(ed.y) * qls[ed.x >> 20];
                if (v != 0.f) atomicAdd(&o2[ed.x & 0xFFFFFu], v);
            }
        }
    }
}

// finish: out[n] = b2 + dinv[n] * (qq[n] + o2[n])   (all dense)
__global__ __launch_bounds__(256) void k_fin2(
    const float* __restrict__ qb, const float* __restrict__ o2,
    const float* __restrict__ dinv, const float* __restrict__ b2,
    float* __restrict__ out, int N) {
    int n = blockIdx.x * 256 + threadIdx.x;
    if (n < N) out[n] = b2[0] + dinv[n] * (qb[n] + o2[n]);
}

extern "C" void kernel_launch(void* const* d_in, const int* in_sizes, int n_in,
                              void* d_out, int out_size, void* d_ws, size_t ws_size,
                              hipStream_t stream) {
    const float* x  = (const float*)d_in[0];
    const int*   ei = (const int*)d_in[1];
    const float* ew = (const float*)d_in[2];
    const float* W1 = (const float*)d_in[3];
    const float* b1 = (const float*)d_in[4];
    const float* W2 = (const float*)d_in[5];
    const float* b2 = (const float*)d_in[6];
    float* out = (float*)d_out;

    const int N = in_sizes[0] / 128;       // 100000
    const int E = in_sizes[2];             // 3200000
    const int* row = ei;
    const int* col = ei + E;
    const int NB = (N + BNODES - 1) >> BSH;   // 1563
    const int NBp = NB_MAX;                   // 1568 (>= NB+1)

    const int hblocks = (E + HCHUNK - 1) / HCHUNK;  // 391
    const int sblocks = (E + CHUNK - 1) / CHUNK;    // 782

    // ---- layout (~82 MB, 256B-aligned fields; < 115 MB HW-proven floor) ----
    char* base = (char*)d_ws;
    size_t off = 0;
    #define ALLOC(ptr_t, name, bytes) \
        ptr_t name = (ptr_t)(base + off); off = (off + (size_t)(bytes) + 255) & ~(size_t)255;
    ALLOC(int*,   gCnt,    (size_t)NBp * 4)
    ALLOC(int*,   rCnt,    (size_t)NBp * 4)
    ALLOC(float*, deg,     (size_t)N * 4)
    ALLOC(int*,   gBase,   (size_t)NBp * 4)
    ALLOC(int*,   rBase,   (size_t)NBp * 4)
    ALLOC(int*,   gCursor, (size_t)NBp * 4)
    ALLOC(int*,   rCursor, (size_t)NBp * 4)
    ALLOC(float*, dinv,    (size_t)N * 4)
    ALLOC(__hip_bfloat16*, hdb, (size_t)16 * N * 2)                 // 3.2 MB
    ALLOC(float*, qb,      (size_t)N * 4)                           // 0.4 MB
    ALLOC(float*, o2,      (size_t)N * 4)                           // 0.4 MB
    ALLOC(float*, partial, (size_t)NB * NSLICE * (DH * BNODES) * 4) // 25.6 MB
    ALLOC(uint2*, edata,   (size_t)E * 8)                           // 25.6 MB
    ALLOC(uint2*, rdata,   (size_t)E * 8)                           // 25.6 MB
    #undef ALLOC

    hipMemsetAsync(gCnt, 0, (size_t)NBp * sizeof(int), stream);
    hipMemsetAsync(rCnt, 0, (size_t)NBp * sizeof(int), stream);
    hipMemsetAsync(deg,  0, (size_t)N * sizeof(float), stream);
    hipMemsetAsync(o2,   0, (size_t)N * sizeof(float), stream);
    k_hist2<<<hblocks, 256, 0, stream>>>(row, col, gCnt, rCnt, E, NB);
    k_Ascan<<<1, 1024, 0, stream>>>(gCnt, gBase, gCursor, NB, E);
    k_Ascan<<<1, 1024, 0, stream>>>(rCnt, rBase, rCursor, NB, E);
    k_Ascatter<<<sblocks, 256, 0, stream>>>(row, col, ew, gCursor, edata, E, NB);
    k_Rscatter2<<<sblocks, 256, 0, stream>>>(row, col, ew, rCursor, rdata, E, NB);
    k_deg<<<dim3(NB, 2), 256, 0, stream>>>(gBase, edata, deg, N);
    k_h1<<<N / 16, 256, 0, stream>>>(x, W1, deg, dinv, hdb);
    k_gather1<<<dim3(NB, NSLICE), 256, 0, stream>>>(gBase, edata, hdb, partial);
    k_fin1b<<<NB, 256, 0, stream>>>(partial, dinv, hdb, b1, W2, qb, N);
    k_gather2s<<<dim3(NB, 2), 256, 0, stream>>>(rBase, rdata, qb, o2, N);
    k_fin2<<<(N + 255) / 256, 256, 0, stream>>>(qb, o2, dinv, b2, out, N);
}